// Round 7
// baseline (186.547 us; speedup 1.0000x reference)
//
#include <hip/hip_runtime.h>
#include <stdint.h>

typedef __attribute__((ext_vector_type(8))) short short8;
typedef __attribute__((ext_vector_type(8))) unsigned short ushort8;
typedef __attribute__((ext_vector_type(4))) unsigned short usv4;
typedef __attribute__((ext_vector_type(4))) float float4v;

#define B_SZ 2
#define SEQ 512
#define D_MODEL 1024
#define D_INNER 2048
#define N_HEADS 32
#define HEAD_DIM 64
#define D_STATE 64
#define PROJ_DIM 8224   // 2*2048 + 2*2048 + 32
#define NPAD 8320       // 65*128
#define MROWS 1024      // B_SZ*SEQ

__device__ __forceinline__ unsigned short f2bf(float f) {
    unsigned u = __builtin_bit_cast(unsigned, f);
    u += 0x7fffu + ((u >> 16) & 1u);
    return (unsigned short)(u >> 16);
}
__device__ __forceinline__ float bf2f(unsigned short h) {
    return __builtin_bit_cast(float, (unsigned)h << 16);
}

// Async global->LDS 16B (m97 path). LDS dest must be wave-uniform base + lane*16.
__device__ __forceinline__ void gld16(unsigned short* lds, const unsigned short* g) {
#if __has_builtin(__builtin_amdgcn_global_load_lds)
    __builtin_amdgcn_global_load_lds(
        (const __attribute__((address_space(1))) void*)g,
        (__attribute__((address_space(3))) void*)lds, 16, 0, 0);
#else
    *(short8*)lds = *(const short8*)g;
#endif
}

// ---------------------------------------------------------------------------
// 64x64 f32->bf16 transpose tile body (shared by prep_fat / pack_fat).
// ---------------------------------------------------------------------------
__device__ void transpose_body(const float* __restrict__ src,
                               unsigned short* __restrict__ dst,
                               int R, int C, int bx, int by, float* T, int tid) {
    int c0 = bx * 64, r0 = by * 64;
    int row = tid >> 2, cg = (tid & 3) * 16;
    #pragma unroll
    for (int k = 0; k < 4; k++) {
        int col = cg + k * 4;
        float4v v;
        if (c0 + col + 3 < C) {
            v = *(const float4v*)&src[(size_t)(r0 + row) * C + c0 + col];
        } else {
            #pragma unroll
            for (int e = 0; e < 4; e++)
                v[e] = (c0 + col + e < C) ? src[(size_t)(r0 + row) * C + c0 + col + e] : 0.f;
        }
        *(float4v*)&T[row * 68 + col] = v;
    }
    __syncthreads();
    int drow = tid >> 2, sg = (tid & 3) * 16;
    ushort8 v[2];
    #pragma unroll
    for (int k = 0; k < 16; k++) v[k >> 3][k & 7] = f2bf(T[(sg + k) * 68 + drow]);
    unsigned short* d = &dst[(size_t)(c0 + drow) * R + r0 + sg];
    *(ushort8*)&d[0] = v[0];
    *(ushort8*)&d[8] = v[1];
}

// ---------------------------------------------------------------------------
// prep: blk<1024 -> hidden f32->bf16; else Wt1 transpose (2080 blocks).
// ---------------------------------------------------------------------------
__global__ __launch_bounds__(256) void prep_fat(
    const float* __restrict__ hidden, const float* __restrict__ W_in,
    unsigned short* __restrict__ Hb, unsigned short* __restrict__ Wt1) {
    __shared__ float T[64 * 68];
    int blk = blockIdx.x, tid = threadIdx.x;
    if (blk < 1024) {
        int i = blk * 1024 + tid * 4;
        float4v v = *(const float4v*)&hidden[i];
        usv4 o;
        #pragma unroll
        for (int k = 0; k < 4; k++) o[k] = f2bf(v[k]);
        *(usv4*)&Hb[i] = o;
    } else {
        int q = blk - 1024;  // 2080 = 130 x 16
        transpose_body(W_in, Wt1, D_MODEL, PROJ_DIM, q % 130, q / 130, T, tid);
    }
}

// ---------------------------------------------------------------------------
// GEMM: C[M][N] = A[M][K] @ Bt[N][K]^T (bf16). 128x128 tile, 4 waves, BK=64,
// 2-PHASE DOUBLE-BUFFERED staging (T3-minimum; same pattern as attn_tile):
// prologue-stage buf0; per iter {barrier; STAGE(buf^1, next); compute(cur)}.
// Barrier at iter i drains loads issued at start of iter i-1 (a full compute
// phase to cover). LDS 64 KB/block -> 2 blocks/CU still fit.
// async global_load_lds + XOR bank swizzle (conflict-free, verified R5).
// Split-K via gridDim.z; BF16OUT selects output type. Atomic-free.
// SWZ: 0 = 2-D grid; 1 = 520-block 1-D grid with B-panel->XCD grouping;
// 2 = 64-block/z 1-D grid 8x8 with same grouping.
// ---------------------------------------------------------------------------
template <bool BF16OUT, int SWZ>
__global__ __launch_bounds__(256) void gemm_bt(
    const unsigned short* __restrict__ A, const unsigned short* __restrict__ Bt,
    void* __restrict__ Cout, int M, int N, int K, int klen) {
    __shared__ unsigned short As[2][8192];
    __shared__ unsigned short Bs[2][8192];
    int tid = threadIdx.x;
    int lane = tid & 63, w = tid >> 6, quad = lane >> 4, l15 = lane & 15;
    int bx, by;
    if (SWZ == 1) {
        int bid = blockIdx.x;
        if (bid < 512) { int g = bid & 7, s = bid >> 3; bx = ((s & 7) << 3) | g; by = s >> 3; }
        else           { bx = 64; by = bid - 512; }
    } else if (SWZ == 2) {
        int bid = blockIdx.x;
        bx = bid & 7; by = bid >> 3;
    } else {
        bx = blockIdx.x; by = blockIdx.y;
    }
    int m0 = by * 128, n0 = bx * 128;
    int kb = blockIdx.z * klen;
    int nit = klen >> 6;
    int wm = (w & 1) * 64, wn = (w >> 1) * 64;
    float4v acc[4][4];
    #pragma unroll
    for (int i = 0; i < 4; i++)
        #pragma unroll
        for (int j = 0; j < 4; j++) acc[i][j] = (float4v){0.f, 0.f, 0.f, 0.f};

    int rs = tid >> 3;
    int gl = ((tid & 7) ^ (rs & 7)) * 8;
    const unsigned short* ap = &A [(size_t)(m0 + rs) * K + gl];
    const unsigned short* bp = &Bt[(size_t)(n0 + rs) * K + gl];
    int rx = l15 & 7;

    // prologue: stage first K-step into buf 0
    #pragma unroll
    for (int p = 0; p < 4; p++) {
        gld16(&As[0][p * 2048 + tid * 8], ap + (size_t)(p * 32) * K + kb);
        gld16(&Bs[0][p * 2048 + tid * 8], bp + (size_t)(p * 32) * K + kb);
    }

    for (int it = 0; it < nit; ++it) {
        int cur = it & 1;
        __syncthreads();  // drains vmcnt -> buf[cur] ready; buf[cur^1] reads done
        if (it + 1 < nit) {
            int nx = cur ^ 1;
            int kn = kb + (it + 1) * 64;
            #pragma unroll
            for (int p = 0; p < 4; p++) {
                gld16(&As[nx][p * 2048 + tid * 8], ap + (size_t)(p * 32) * K + kn);
                gld16(&Bs[nx][p * 2048 + tid * 8], bp + (size_t)(p * 32) * K + kn);
            }
        }
        #pragma unroll
        for (int kq = 0; kq < 2; kq++) {
            short8 af[4], bfr[4];
            #pragma unroll
            for (int mt = 0; mt < 4; mt++)
                af[mt] = *(const short8*)&As[cur][(wm + mt * 16 + l15) * 64 + (((kq << 2) + quad) ^ rx) * 8];
            #pragma unroll
            for (int nt = 0; nt < 4; nt++)
                bfr[nt] = *(const short8*)&Bs[cur][(wn + nt * 16 + l15) * 64 + (((kq << 2) + quad) ^ rx) * 8];
            #pragma unroll
            for (int mt = 0; mt < 4; mt++)
                #pragma unroll
                for (int nt = 0; nt < 4; nt++)
                    acc[mt][nt] = __builtin_amdgcn_mfma_f32_16x16x32_bf16(
                        af[mt], bfr[nt], acc[mt][nt], 0, 0, 0);
        }
    }
    #pragma unroll
    for (int mt = 0; mt < 4; mt++)
        #pragma unroll
        for (int nt = 0; nt < 4; nt++)
            #pragma unroll
            for (int r = 0; r < 4; r++) {
                int row = m0 + wm + mt * 16 + quad * 4 + r;
                int col = n0 + wn + nt * 16 + l15;
                if (col < N) {
                    if (BF16OUT)
                        ((unsigned short*)Cout)[(size_t)row * N + col] = f2bf(acc[mt][nt][r]);
                    else
                        ((float*)Cout)[(size_t)blockIdx.z * M * N + (size_t)row * N + col]
                            = acc[mt][nt][r];
                }
            }
}

// ---------------------------------------------------------------------------
// reduce 4 split-K partials -> f32 out.
// ---------------------------------------------------------------------------
__global__ __launch_bounds__(256) void reduce4(
    const float* __restrict__ P, float* __restrict__ out, int n) {
    int i = (blockIdx.x * 256 + threadIdx.x) * 4;
    float4v s = *(const float4v*)&P[i];
    #pragma unroll
    for (int z = 1; z < 4; z++) {
        float4v v = *(const float4v*)&P[(size_t)z * n + i];
        #pragma unroll
        for (int k = 0; k < 4; k++) s[k] += v[k];
    }
    *(float4v*)&out[i] = s;
}

// ---------------------------------------------------------------------------
// dt softplus + cumsum per (b,h): 64 blocks x 256 threads (4 waves x 2
// chunks), 2-round parallel prefix (wave scans + 8-entry chunk-total scan).
// ---------------------------------------------------------------------------
__global__ __launch_bounds__(256) void dt_scan(
    const unsigned short* __restrict__ proj, const float* __restrict__ dt_bias,
    float* __restrict__ dt_arr, float* __restrict__ cum_arr) {
    __shared__ float chs[8];
    int bh = blockIdx.x;
    int b = bh >> 5, h = bh & 31;
    int tid = threadIdx.x, lane = tid & 63, w = tid >> 6;
    float bias = dt_bias[h];
    int t0 = w * 64 + lane, t1 = 256 + w * 64 + lane;
    float raw0 = bf2f(proj[(size_t)(b * SEQ + t0) * PROJ_DIM + 8192 + h]) + bias;
    float raw1 = bf2f(proj[(size_t)(b * SEQ + t1) * PROJ_DIM + 8192 + h]) + bias;
    float dt0 = raw0 > 20.f ? raw0 : log1pf(expf(raw0));
    float dt1 = raw1 > 20.f ? raw1 : log1pf(expf(raw1));
    float v0 = dt0, v1 = dt1;
    #pragma unroll
    for (int d = 1; d < 64; d <<= 1) {
        float n0 = __shfl_up(v0, d, 64);
        float n1 = __shfl_up(v1, d, 64);
        if (lane >= d) { v0 += n0; v1 += n1; }
    }
    if (lane == 63) { chs[w] = v0; chs[4 + w] = v1; }
    __syncthreads();
    float off0 = 0.f, off1 = 0.f;
    #pragma unroll
    for (int c = 0; c < 8; c++) {
        float s = chs[c];
        if (c < w) off0 += s;
        if (c < 4 + w) off1 += s;
    }
    dt_arr[bh * SEQ + t0] = dt0;  cum_arr[bh * SEQ + t0] = off0 + v0;
    dt_arr[bh * SEQ + t1] = dt1;  cum_arr[bh * SEQ + t1] = off1 + v1;
}

// ---------------------------------------------------------------------------
// pack_fat: blk<1024 -> RoPE pack B,C for row m=blk (b,t); blk<1536 ->
// x-transpose chunk (512 blocks) -> Xt[bh][p][s] bf16; blk<2048 -> Wt2
// transpose (512 blocks, off gemm1's critical path).
// ---------------------------------------------------------------------------
__global__ __launch_bounds__(256) void pack_fat(
    const unsigned short* __restrict__ proj, const float* __restrict__ cum_arr,
    const float* __restrict__ W_out,
    unsigned short* __restrict__ Bh, unsigned short* __restrict__ Ch,
    unsigned short* __restrict__ Xt, unsigned short* __restrict__ Wt2) {
    __shared__ float T[64 * 68];
    unsigned short* XT = (unsigned short*)T;
    int blk = blockIdx.x, tid = threadIdx.x;
    if (blk < 1024) {
        int m = blk, b = m >> 9, t = m & 511;
        const float k_l2 = 13.287712379549449f / 32.f;  // log2(10000)/half
        #pragma unroll
        for (int i = 0; i < 4; i++) {
            int q = i * 256 + tid;
            int h = q >> 5, j = q & 31;
            float cum = cum_arr[(b * 32 + h) * SEQ + t];
            float th = cum * exp2f(-(float)j * k_l2);
            float s, c;
            __sincosf(th, &s, &c);
            size_t rb = (size_t)m * PROJ_DIM;
            unsigned bu = *(const unsigned*)&proj[rb + 4096 + h * 64 + 2 * j];
            unsigned cu = *(const unsigned*)&proj[rb + 6144 + h * 64 + 2 * j];
            float b0 = bf2f((unsigned short)(bu & 0xffff)), b1 = bf2f((unsigned short)(bu >> 16));
            float c0 = bf2f((unsigned short)(cu & 0xffff)), c1 = bf2f((unsigned short)(cu >> 16));
            size_t dst = ((size_t)(b * 32 + h) * SEQ + t) * 64 + 2 * j;
            unsigned ob = (unsigned)f2bf(b0 * c - b1 * s) | ((unsigned)f2bf(b0 * s + b1 * c) << 16);
            unsigned oc = (unsigned)f2bf(c0 * c - c1 * s) | ((unsigned)f2bf(c0 * s + c1 * c) << 16);
            *(unsigned*)&Bh[dst] = ob;
            *(unsigned*)&Ch[dst] = oc;
        }
    } else if (blk < 1536) {
        int q = blk - 1024;
        int bh = q >> 3, s0 = (q & 7) * 64;
        int b = bh >> 5, h = bh & 31;
        int r = tid >> 2, cg = (tid & 3) * 16;
        const unsigned short* src = &proj[(size_t)(b * SEQ + s0 + r) * PROJ_DIM + 2048 + h * 64 + cg];
        *(ushort8*)&XT[r * 72 + cg]     = *(const ushort8*)&src[0];
        *(ushort8*)&XT[r * 72 + cg + 8] = *(const ushort8*)&src[8];
        __syncthreads();
        int p = tid >> 2, sg = (tid & 3) * 16;
        ushort8 v[2];
        #pragma unroll
        for (int k = 0; k < 16; k++) v[k >> 3][k & 7] = XT[(sg + k) * 72 + p];
        unsigned short* dst = &Xt[((size_t)bh * 64 + p) * SEQ + s0 + sg];
        *(ushort8*)&dst[0] = v[0];
        *(ushort8*)&dst[8] = v[1];
    } else {
        int q = blk - 1536;  // 512 = 16 x 32
        transpose_body(W_out, Wt2, D_INNER, D_MODEL, q % 16, q / 16, T, tid);
    }
}

// ---------------------------------------------------------------------------
// Decay-attention, up to FOUR (qt,st) tiles per block, ATOMIC-FREE, with
// double-buffered issue-early staging. slot = st-group index within qt (<=2).
// Disjoint y_part regions per (qt,slot,bh); gated_rmsnorm sums ns(t) slots.
// grid (12 slot-blocks, 64 bh), 256 threads (4 waves x 16 q-rows).
// ---------------------------------------------------------------------------
__global__ __launch_bounds__(256) void attn_tile(
    const unsigned short* __restrict__ Bh, const unsigned short* __restrict__ Ch,
    const unsigned short* __restrict__ Xt, const float* __restrict__ dt_arr,
    const float* __restrict__ cum_arr, const float* __restrict__ A_log,
    float* __restrict__ y_part) {
    __shared__ unsigned short Bs[2][4096];
    __shared__ unsigned short Xs[2][4096];
    __shared__ unsigned short Ps[4096];
    // decode slot index -> (qt, slot): qt has ceil((qt+1)/4) slot-blocks
    int pid = blockIdx.x;
    int qt = 0;
    while (pid >= ((qt + 4) >> 2)) { pid -= ((qt + 4) >> 2); qt++; }
    int slot = pid;
    int st0 = slot * 4;
    int nst = qt - st0 + 1; if (nst > 4) nst = 4;
    int bh = blockIdx.y;
    int b = bh >> 5, h = bh & 31;
    float Aneg = -expf(A_log[h]);
    int tid = threadIdx.x, lane = tid & 63, w = tid >> 6;
    int quad = lane >> 4, l15 = lane & 15;
    int rx = l15 & 7;

    int srow = tid >> 3, sg = tid & 7;
    int swz = (sg ^ (srow & 7)) * 8;
    int swz2 = (sg ^ ((srow + 32) & 7)) * 8;

    // prologue: stage first tile into buf 0
    {
        const unsigned short* bsrc = Bh + ((size_t)bh * SEQ + st0 * 64) * 64;
        gld16(&Bs[0][tid * 8],         bsrc + srow * 64 + swz);
        gld16(&Bs[0][(tid + 256) * 8], bsrc + (srow + 32) * 64 + swz2);
        const unsigned short* xsrc = Xt + (size_t)bh * 64 * SEQ + st0 * 64;
        gld16(&Xs[0][tid * 8],         xsrc + (size_t)srow * SEQ + swz);
        gld16(&Xs[0][(tid + 256) * 8], xsrc + (size_t)(srow + 32) * SEQ + swz2);
    }

    int qrow = qt * 64 + w * 16 + l15;
    const unsigned short* Cptr = Ch + ((size_t)bh * SEQ + qrow) * 64;
    short8 cf[2];
    cf[0] = *(const short8*)&Cptr[quad * 8];
    cf[1] = *(const short8*)&Cptr[32 + quad * 8];

    int trow[4];
    float cumt[4];
    #pragma unroll
    for (int r = 0; r < 4; r++) {
        trow[r] = qt * 64 + w * 16 + quad * 4 + r;
        cumt[r] = cum_arr[bh * SEQ + trow[r]];
    }
    float4v yacc[4];
    #pragma unroll
    for (int i = 0; i < 4; i++) yacc[i] = (float4v){0.f, 0.f, 0.f, 0.f};

    for (int si = 0; si < nst; si++) {
        int st = st0 + si;
        int cur = si & 1;
        __syncthreads();  // drains gld16 vmcnt -> buf[cur] published
        if (si + 1 < nst) {
            int nx = cur ^ 1;
            int stn = st + 1;
            const unsigned short* bsrc = Bh + ((size_t)bh * SEQ + stn * 64) * 64;
            gld16(&Bs[nx][tid * 8],         bsrc + srow * 64 + swz);
            gld16(&Bs[nx][(tid + 256) * 8], bsrc + (srow + 32) * 64 + swz2);
            const unsigned short* xsrc = Xt + (size_t)bh * 64 * SEQ + stn * 64;
            gld16(&Xs[nx][tid * 8],         xsrc + (size_t)srow * SEQ + swz);
            gld16(&Xs[nx][(tid + 256) * 8], xsrc + (size_t)(srow + 32) * SEQ + swz2);
        }

        // scores S[t][s] = C_t . B_s
        float4v sacc[4];
        #pragma unroll
        for (int i = 0; i < 4; i++) sacc[i] = (float4v){0.f, 0.f, 0.f, 0.f};
        #pragma unroll
        for (int kk = 0; kk < 2; kk++)
            #pragma unroll
            for (int nt = 0; nt < 4; nt++) {
                short8 bf8 = *(const short8*)&Bs[cur][(nt * 16 + l15) * 64 + (((kk << 2) + quad) ^ rx) * 8];
                sacc[nt] = __builtin_amdgcn_mfma_f32_16x16x32_bf16(cf[kk], bf8, sacc[nt], 0, 0, 0);
            }
        // weight + pack P (bf16) into per-wave swizzled LDS region
        #pragma unroll
        for (int nt = 0; nt < 4; nt++) {
            int s = st * 64 + nt * 16 + l15;
            float cums = cum_arr[bh * SEQ + s];
            float dts = dt_arr[bh * SEQ + s];
            float dts1 = (s + 1 < SEQ) ? dt_arr[bh * SEQ + s + 1] : 0.f;
            #pragma unroll
            for (int r = 0; r < 4; r++) {
                int t = trow[r];
                float wgt = (s > t) ? 0.f
                          : expf(Aneg * (cumt[r] - cums)) * 0.5f * (dts + ((s < t) ? dts1 : 0.f));
                int row = quad * 4 + r;
                int col = nt * 16 + l15;
                Ps[w * 1024 + row * 64 + (((col >> 3) ^ (row & 7)) << 3) + (col & 7)]
                    = f2bf(sacc[nt][r] * wgt);
            }
        }
        // Ps is per-wave private: same-wave lgkmcnt ordering suffices, no barrier.
        #pragma unroll
        for (int kk = 0; kk < 2; kk++) {
            short8 af = *(const short8*)&Ps[w * 1024 + l15 * 64 + (((kk << 2) + quad) ^ rx) * 8];
            #pragma unroll
            for (int pt = 0; pt < 4; pt++) {
                short8 xf = *(const short8*)&Xs[cur][(pt * 16 + l15) * 64 + (((kk << 2) + quad) ^ rx) * 8];
                yacc[pt] = __builtin_amdgcn_mfma_f32_16x16x32_bf16(af, xf, yacc[pt], 0, 0, 0);
            }
        }
    }
    float* yp = y_part + (size_t)slot * ((size_t)MROWS * D_INNER);
    #pragma unroll
    for (int pt = 0; pt < 4; pt++)
        #pragma unroll
        for (int r = 0; r < 4; r++) {
            int t = trow[r];
            int p = pt * 16 + l15;
            yp[((size_t)b * SEQ + t) * D_INNER + h * 64 + p] = yacc[pt][r];
        }
}

// ---------------------------------------------------------------------------
// y = (sum of ns(t) slot partials) * silu(z); rmsnorm; write bf16.
// ns(t) = ceil((t/64 + 1)/4). 1024 blocks x 256 thr.
// ---------------------------------------------------------------------------
__global__ __launch_bounds__(256) void gated_rmsnorm(
    const float* __restrict__ y_part, const unsigned short* __restrict__ proj,
    const float* __restrict__ nw, unsigned short* __restrict__ Y2) {
    __shared__ float red[4];
    int m = blockIdx.x, tid = threadIdx.x;
    int t = m & 511;
    int ns = ((t >> 6) + 4) >> 2;
    const unsigned short* zrow = proj + (size_t)m * PROJ_DIM;
    int j0 = tid * 8;
    float acc8[8];
    #pragma unroll
    for (int k = 0; k < 8; k++) acc8[k] = 0.f;
    for (int p = 0; p < ns; p++) {
        const float* yr = y_part + (size_t)p * ((size_t)MROWS * D_INNER) + (size_t)m * D_INNER + j0;
        float4v a = *(const float4v*)&yr[0];
        float4v c = *(const float4v*)&yr[4];
        acc8[0] += a[0]; acc8[1] += a[1]; acc8[2] += a[2]; acc8[3] += a[3];
        acc8[4] += c[0]; acc8[5] += c[1]; acc8[6] += c[2]; acc8[7] += c[3];
    }
    ushort8 zv = *(const ushort8*)&zrow[j0];
    float v[8];
    float ss = 0.f;
    #pragma unroll
    for (int k = 0; k < 8; k++) {
        float y = acc8[k];
        float z = bf2f(zv[k]);
        float g = y * (z / (1.f + expf(-z)));
        v[k] = g;
        ss += g * g;
    }
    #pragma unroll
    for (int d = 32; d > 0; d >>= 1) ss += __shfl_down(ss, d, 64);
    if ((tid & 63) == 0) red[tid >> 6] = ss;
    __syncthreads();
    float tot = red[0] + red[1] + red[2] + red[3];
    float inv = 1.0f / sqrtf(tot / (float)D_INNER + 1e-6f);
    #pragma unroll
    for (int k = 0; k < 8; k++)
        Y2[(size_t)m * D_INNER + j0 + k] = f2bf(v[k] * inv * nw[j0 + k]);
}

// ---------------------------------------------------------------------------

extern "C" void kernel_launch(void* const* d_in, const int* in_sizes, int n_in,
                              void* d_out, int out_size, void* d_ws, size_t ws_size,
                              hipStream_t stream) {
    const float* hidden   = (const float*)d_in[0];
    const float* W_in     = (const float*)d_in[1];
    const float* dt_bias  = (const float*)d_in[2];
    const float* A_log    = (const float*)d_in[3];
    const float* norm_w   = (const float*)d_in[4];
    const float* W_out    = (const float*)d_in[5];
    float* out = (float*)d_out;

    char* ws = (char*)d_ws;
    unsigned short* Wt1  = (unsigned short*)(ws);                // 8320*1024 bf16 = 17,039,360
    unsigned short* Hb   = (unsigned short*)(ws + 17039360);     // 1024*1024 bf16 = 2,097,152
    unsigned short* proj = (unsigned short*)(ws + 19136512);     // 1024*8224 bf16 = 16,842,752
    float* dt_arr        = (float*)(ws + 35979264);              // 131,072
    float* cum_arr       = (float*)(ws + 36110336);              // 131,072
    unsigned short* Bh   = (unsigned short*)(ws + 36241408);     // 4,194,304
    unsigned short* Ch   = (unsigned short*)(ws + 40435712);     // 4,194,304
    unsigned short* Xt   = (unsigned short*)(ws + 44630016);     // 4,194,304
    unsigned short* Y2   = (unsigned short*)(ws + 57212928);     // 4,194,304
    unsigned short* Wt2  = (unsigned short*)(ws + 61407232);     // 4,194,304
    float* y_part        = (float*)(ws + 65601536);              // 2 x 8,388,608 = 16,777,216
    // total 82,378,752 bytes (ws poison is 256 MiB per harness)
    float* Pk = (float*)proj;  // 16 MB split-K partials fit in 16.8 MB proj (free by then)

    // prep: hidden cast (1024) + Wt1 transpose (2080)
    prep_fat<<<3104, 256, 0, stream>>>(hidden, W_in, Hb, Wt1);
    // proj = hidden @ W_in (bf16 out, guarded at N=8224), B-panel XCD grouping
    gemm_bt<true, 1><<<dim3(520, 1, 1), 256, 0, stream>>>(
        Hb, Wt1, proj, MROWS, PROJ_DIM, D_MODEL, D_MODEL);
    // dt + cumsum (2-round parallel prefix)
    dt_scan<<<64, 256, 0, stream>>>(proj, dt_bias, dt_arr, cum_arr);
    // rope pack (1024) + x transpose (512) + Wt2 transpose (512)
    pack_fat<<<2048, 256, 0, stream>>>(proj, cum_arr, W_out, Bh, Ch, Xt, Wt2);
    // decay attention: up to 4 (qt,st) tiles per block, dbuf staging,
    // slot-partial stores
    attn_tile<<<dim3(12, 64), 256, 0, stream>>>(Bh, Ch, Xt, dt_arr, cum_arr, A_log, y_part);
    // gate + rmsnorm, inline <=2-slot reduction (last reader of proj/z)
    gated_rmsnorm<<<MROWS, 256, 0, stream>>>(y_part, proj, norm_w, Y2);
    // out = Y2 @ W_out, split-K=4 partials into Pk (B-panel XCD grouping),
    // then reduce
    gemm_bt<false, 2><<<dim3(64, 1, 4), 256, 0, stream>>>(
        Y2, Wt2, Pk, MROWS, D_MODEL, D_INNER, D_INNER / 4);
    reduce4<<<MROWS * D_MODEL / 1024, 256, 0, stream>>>(Pk, out, MROWS * D_MODEL);
}

// Round 8
// 180.793 us; speedup vs baseline: 1.0318x; 1.0318x over previous
//
#include <hip/hip_runtime.h>
#include <stdint.h>

typedef __attribute__((ext_vector_type(8))) short short8;
typedef __attribute__((ext_vector_type(8))) unsigned short ushort8;
typedef __attribute__((ext_vector_type(4))) unsigned short usv4;
typedef __attribute__((ext_vector_type(4))) float float4v;

#define B_SZ 2
#define SEQ 512
#define D_MODEL 1024
#define D_INNER 2048
#define N_HEADS 32
#define HEAD_DIM 64
#define D_STATE 64
#define PROJ_DIM 8224   // 2*2048 + 2*2048 + 32
#define NPAD 8320       // 65*128
#define MROWS 1024      // B_SZ*SEQ

__device__ __forceinline__ unsigned short f2bf(float f) {
    unsigned u = __builtin_bit_cast(unsigned, f);
    u += 0x7fffu + ((u >> 16) & 1u);
    return (unsigned short)(u >> 16);
}
__device__ __forceinline__ float bf2f(unsigned short h) {
    return __builtin_bit_cast(float, (unsigned)h << 16);
}

// Async global->LDS 16B (m97 path). LDS dest must be wave-uniform base + lane*16.
__device__ __forceinline__ void gld16(unsigned short* lds, const unsigned short* g) {
#if __has_builtin(__builtin_amdgcn_global_load_lds)
    __builtin_amdgcn_global_load_lds(
        (const __attribute__((address_space(1))) void*)g,
        (__attribute__((address_space(3))) void*)lds, 16, 0, 0);
#else
    *(short8*)lds = *(const short8*)g;
#endif
}

// ---------------------------------------------------------------------------
// 64x64 f32->bf16 transpose tile body (shared by prep_fat / pack_fat).
// ---------------------------------------------------------------------------
__device__ void transpose_body(const float* __restrict__ src,
                               unsigned short* __restrict__ dst,
                               int R, int C, int bx, int by, float* T, int tid) {
    int c0 = bx * 64, r0 = by * 64;
    int row = tid >> 2, cg = (tid & 3) * 16;
    #pragma unroll
    for (int k = 0; k < 4; k++) {
        int col = cg + k * 4;
        float4v v;
        if (c0 + col + 3 < C) {
            v = *(const float4v*)&src[(size_t)(r0 + row) * C + c0 + col];
        } else {
            #pragma unroll
            for (int e = 0; e < 4; e++)
                v[e] = (c0 + col + e < C) ? src[(size_t)(r0 + row) * C + c0 + col + e] : 0.f;
        }
        *(float4v*)&T[row * 68 + col] = v;
    }
    __syncthreads();
    int drow = tid >> 2, sg = (tid & 3) * 16;
    ushort8 v[2];
    #pragma unroll
    for (int k = 0; k < 16; k++) v[k >> 3][k & 7] = f2bf(T[(sg + k) * 68 + drow]);
    unsigned short* d = &dst[(size_t)(c0 + drow) * R + r0 + sg];
    *(ushort8*)&d[0] = v[0];
    *(ushort8*)&d[8] = v[1];
}

// ---------------------------------------------------------------------------
// prep: blk<1024 -> hidden f32->bf16; else Wt1 transpose (2080 blocks).
// ---------------------------------------------------------------------------
__global__ __launch_bounds__(256) void prep_fat(
    const float* __restrict__ hidden, const float* __restrict__ W_in,
    unsigned short* __restrict__ Hb, unsigned short* __restrict__ Wt1) {
    __shared__ float T[64 * 68];
    int blk = blockIdx.x, tid = threadIdx.x;
    if (blk < 1024) {
        int i = blk * 1024 + tid * 4;
        float4v v = *(const float4v*)&hidden[i];
        usv4 o;
        #pragma unroll
        for (int k = 0; k < 4; k++) o[k] = f2bf(v[k]);
        *(usv4*)&Hb[i] = o;
    } else {
        int q = blk - 1024;  // 2080 = 130 x 16
        transpose_body(W_in, Wt1, D_MODEL, PROJ_DIM, q % 130, q / 130, T, tid);
    }
}

// ---------------------------------------------------------------------------
// GEMM: C[M][N] = A[M][K] @ Bt[N][K]^T (bf16). 128x64 tile, 4 waves (each
// owning 32 M-rows x 64 N-cols), BK=64, single-buffered m97 structure
// (stage -> barrier -> compute -> barrier). 24 KB LDS -> >=4 blocks/CU
// resident at these grids; cross-block overlap hides staging latency
// (R7 post-mortem: 2-phase dbuf at 64 KB LDS dropped to 1 block/CU, -20%).
// XOR bank swizzle via pre-swizzled global source (verified R4/R6; row-XOR
// unchanged since tile rows == rows mod 8).
// Split-K via gridDim.z; BF16OUT selects output type. Atomic-free.
// ---------------------------------------------------------------------------
template <bool BF16OUT>
__global__ __launch_bounds__(256) void gemm_bt(
    const unsigned short* __restrict__ A, const unsigned short* __restrict__ Bt,
    void* __restrict__ Cout, int M, int N, int K, int klen) {
    __shared__ unsigned short As[8192];  // 128 x 64
    __shared__ unsigned short Bs[4096];  // 64 x 64
    int tid = threadIdx.x;
    int lane = tid & 63, w = tid >> 6, quad = lane >> 4, l15 = lane & 15;
    int m0 = blockIdx.y * 128, n0 = blockIdx.x * 64;
    int kb = blockIdx.z * klen, ke = kb + klen;
    int wm = w * 32;
    float4v acc[2][4];
    #pragma unroll
    for (int i = 0; i < 2; i++)
        #pragma unroll
        for (int j = 0; j < 4; j++) acc[i][j] = (float4v){0.f, 0.f, 0.f, 0.f};

    int rs = tid >> 3;
    int gl = ((tid & 7) ^ (rs & 7)) * 8;
    const unsigned short* ap = &A [(size_t)(m0 + rs) * K + gl];
    const unsigned short* bp = &Bt[(size_t)(n0 + rs) * K + gl];
    int rx = l15 & 7;

    for (int k0 = kb; k0 < ke; k0 += 64) {
        __syncthreads();
        #pragma unroll
        for (int p = 0; p < 4; p++)
            gld16(&As[p * 2048 + tid * 8], ap + (size_t)(p * 32) * K + k0);
        #pragma unroll
        for (int p = 0; p < 2; p++)
            gld16(&Bs[p * 2048 + tid * 8], bp + (size_t)(p * 32) * K + k0);
        __syncthreads();
        #pragma unroll
        for (int kq = 0; kq < 2; kq++) {
            short8 af[2], bfr[4];
            #pragma unroll
            for (int mt = 0; mt < 2; mt++)
                af[mt] = *(const short8*)&As[(wm + mt * 16 + l15) * 64 + (((kq << 2) + quad) ^ rx) * 8];
            #pragma unroll
            for (int nt = 0; nt < 4; nt++)
                bfr[nt] = *(const short8*)&Bs[(nt * 16 + l15) * 64 + (((kq << 2) + quad) ^ rx) * 8];
            #pragma unroll
            for (int mt = 0; mt < 2; mt++)
                #pragma unroll
                for (int nt = 0; nt < 4; nt++)
                    acc[mt][nt] = __builtin_amdgcn_mfma_f32_16x16x32_bf16(
                        af[mt], bfr[nt], acc[mt][nt], 0, 0, 0);
        }
    }
    #pragma unroll
    for (int mt = 0; mt < 2; mt++)
        #pragma unroll
        for (int nt = 0; nt < 4; nt++)
            #pragma unroll
            for (int r = 0; r < 4; r++) {
                int row = m0 + wm + mt * 16 + quad * 4 + r;
                int col = n0 + nt * 16 + l15;
                if (col < N) {
                    if (BF16OUT)
                        ((unsigned short*)Cout)[(size_t)row * N + col] = f2bf(acc[mt][nt][r]);
                    else
                        ((float*)Cout)[(size_t)blockIdx.z * M * N + (size_t)row * N + col]
                            = acc[mt][nt][r];
                }
            }
}

// ---------------------------------------------------------------------------
// reduce 4 split-K partials -> f32 out.
// ---------------------------------------------------------------------------
__global__ __launch_bounds__(256) void reduce4(
    const float* __restrict__ P, float* __restrict__ out, int n) {
    int i = (blockIdx.x * 256 + threadIdx.x) * 4;
    float4v s = *(const float4v*)&P[i];
    #pragma unroll
    for (int z = 1; z < 4; z++) {
        float4v v = *(const float4v*)&P[(size_t)z * n + i];
        #pragma unroll
        for (int k = 0; k < 4; k++) s[k] += v[k];
    }
    *(float4v*)&out[i] = s;
}

// ---------------------------------------------------------------------------
// dt softplus + cumsum per (b,h): 64 blocks x 256 threads (4 waves x 2
// chunks), 2-round parallel prefix (wave scans + 8-entry chunk-total scan).
// ---------------------------------------------------------------------------
__global__ __launch_bounds__(256) void dt_scan(
    const unsigned short* __restrict__ proj, const float* __restrict__ dt_bias,
    float* __restrict__ dt_arr, float* __restrict__ cum_arr) {
    __shared__ float chs[8];
    int bh = blockIdx.x;
    int b = bh >> 5, h = bh & 31;
    int tid = threadIdx.x, lane = tid & 63, w = tid >> 6;
    float bias = dt_bias[h];
    int t0 = w * 64 + lane, t1 = 256 + w * 64 + lane;
    float raw0 = bf2f(proj[(size_t)(b * SEQ + t0) * PROJ_DIM + 8192 + h]) + bias;
    float raw1 = bf2f(proj[(size_t)(b * SEQ + t1) * PROJ_DIM + 8192 + h]) + bias;
    float dt0 = raw0 > 20.f ? raw0 : log1pf(expf(raw0));
    float dt1 = raw1 > 20.f ? raw1 : log1pf(expf(raw1));
    float v0 = dt0, v1 = dt1;
    #pragma unroll
    for (int d = 1; d < 64; d <<= 1) {
        float n0 = __shfl_up(v0, d, 64);
        float n1 = __shfl_up(v1, d, 64);
        if (lane >= d) { v0 += n0; v1 += n1; }
    }
    if (lane == 63) { chs[w] = v0; chs[4 + w] = v1; }
    __syncthreads();
    float off0 = 0.f, off1 = 0.f;
    #pragma unroll
    for (int c = 0; c < 8; c++) {
        float s = chs[c];
        if (c < w) off0 += s;
        if (c < 4 + w) off1 += s;
    }
    dt_arr[bh * SEQ + t0] = dt0;  cum_arr[bh * SEQ + t0] = off0 + v0;
    dt_arr[bh * SEQ + t1] = dt1;  cum_arr[bh * SEQ + t1] = off1 + v1;
}

// ---------------------------------------------------------------------------
// pack_fat: blk<1024 -> RoPE pack B,C for row m=blk (b,t); blk<1536 ->
// x-transpose chunk (512 blocks) -> Xt[bh][p][s] bf16; blk<2048 -> Wt2
// transpose (512 blocks, off gemm1's critical path).
// ---------------------------------------------------------------------------
__global__ __launch_bounds__(256) void pack_fat(
    const unsigned short* __restrict__ proj, const float* __restrict__ cum_arr,
    const float* __restrict__ W_out,
    unsigned short* __restrict__ Bh, unsigned short* __restrict__ Ch,
    unsigned short* __restrict__ Xt, unsigned short* __restrict__ Wt2) {
    __shared__ float T[64 * 68];
    unsigned short* XT = (unsigned short*)T;
    int blk = blockIdx.x, tid = threadIdx.x;
    if (blk < 1024) {
        int m = blk, b = m >> 9, t = m & 511;
        const float k_l2 = 13.287712379549449f / 32.f;  // log2(10000)/half
        #pragma unroll
        for (int i = 0; i < 4; i++) {
            int q = i * 256 + tid;
            int h = q >> 5, j = q & 31;
            float cum = cum_arr[(b * 32 + h) * SEQ + t];
            float th = cum * exp2f(-(float)j * k_l2);
            float s, c;
            __sincosf(th, &s, &c);
            size_t rb = (size_t)m * PROJ_DIM;
            unsigned bu = *(const unsigned*)&proj[rb + 4096 + h * 64 + 2 * j];
            unsigned cu = *(const unsigned*)&proj[rb + 6144 + h * 64 + 2 * j];
            float b0 = bf2f((unsigned short)(bu & 0xffff)), b1 = bf2f((unsigned short)(bu >> 16));
            float c0 = bf2f((unsigned short)(cu & 0xffff)), c1 = bf2f((unsigned short)(cu >> 16));
            size_t dst = ((size_t)(b * 32 + h) * SEQ + t) * 64 + 2 * j;
            unsigned ob = (unsigned)f2bf(b0 * c - b1 * s) | ((unsigned)f2bf(b0 * s + b1 * c) << 16);
            unsigned oc = (unsigned)f2bf(c0 * c - c1 * s) | ((unsigned)f2bf(c0 * s + c1 * c) << 16);
            *(unsigned*)&Bh[dst] = ob;
            *(unsigned*)&Ch[dst] = oc;
        }
    } else if (blk < 1536) {
        int q = blk - 1024;
        int bh = q >> 3, s0 = (q & 7) * 64;
        int b = bh >> 5, h = bh & 31;
        int r = tid >> 2, cg = (tid & 3) * 16;
        const unsigned short* src = &proj[(size_t)(b * SEQ + s0 + r) * PROJ_DIM + 2048 + h * 64 + cg];
        *(ushort8*)&XT[r * 72 + cg]     = *(const ushort8*)&src[0];
        *(ushort8*)&XT[r * 72 + cg + 8] = *(const ushort8*)&src[8];
        __syncthreads();
        int p = tid >> 2, sg = (tid & 3) * 16;
        ushort8 v[2];
        #pragma unroll
        for (int k = 0; k < 16; k++) v[k >> 3][k & 7] = XT[(sg + k) * 72 + p];
        unsigned short* dst = &Xt[((size_t)bh * 64 + p) * SEQ + s0 + sg];
        *(ushort8*)&dst[0] = v[0];
        *(ushort8*)&dst[8] = v[1];
    } else {
        int q = blk - 1536;  // 512 = 16 x 32
        transpose_body(W_out, Wt2, D_INNER, D_MODEL, q % 16, q / 16, T, tid);
    }
}

// ---------------------------------------------------------------------------
// Decay-attention, up to FOUR (qt,st) tiles per block, ATOMIC-FREE, with
// double-buffered issue-early staging. slot = st-group index within qt (<=2).
// Disjoint y_part regions per (qt,slot,bh); gated_rmsnorm sums ns(t) slots.
// grid (12 slot-blocks, 64 bh), 256 threads (4 waves x 16 q-rows).
// ---------------------------------------------------------------------------
__global__ __launch_bounds__(256) void attn_tile(
    const unsigned short* __restrict__ Bh, const unsigned short* __restrict__ Ch,
    const unsigned short* __restrict__ Xt, const float* __restrict__ dt_arr,
    const float* __restrict__ cum_arr, const float* __restrict__ A_log,
    float* __restrict__ y_part) {
    __shared__ unsigned short Bs[2][4096];
    __shared__ unsigned short Xs[2][4096];
    __shared__ unsigned short Ps[4096];
    // decode slot index -> (qt, slot): qt has ceil((qt+1)/4) slot-blocks
    int pid = blockIdx.x;
    int qt = 0;
    while (pid >= ((qt + 4) >> 2)) { pid -= ((qt + 4) >> 2); qt++; }
    int slot = pid;
    int st0 = slot * 4;
    int nst = qt - st0 + 1; if (nst > 4) nst = 4;
    int bh = blockIdx.y;
    int b = bh >> 5, h = bh & 31;
    float Aneg = -expf(A_log[h]);
    int tid = threadIdx.x, lane = tid & 63, w = tid >> 6;
    int quad = lane >> 4, l15 = lane & 15;
    int rx = l15 & 7;

    int srow = tid >> 3, sg = tid & 7;
    int swz = (sg ^ (srow & 7)) * 8;
    int swz2 = (sg ^ ((srow + 32) & 7)) * 8;

    // prologue: stage first tile into buf 0
    {
        const unsigned short* bsrc = Bh + ((size_t)bh * SEQ + st0 * 64) * 64;
        gld16(&Bs[0][tid * 8],         bsrc + srow * 64 + swz);
        gld16(&Bs[0][(tid + 256) * 8], bsrc + (srow + 32) * 64 + swz2);
        const unsigned short* xsrc = Xt + (size_t)bh * 64 * SEQ + st0 * 64;
        gld16(&Xs[0][tid * 8],         xsrc + (size_t)srow * SEQ + swz);
        gld16(&Xs[0][(tid + 256) * 8], xsrc + (size_t)(srow + 32) * SEQ + swz2);
    }

    int qrow = qt * 64 + w * 16 + l15;
    const unsigned short* Cptr = Ch + ((size_t)bh * SEQ + qrow) * 64;
    short8 cf[2];
    cf[0] = *(const short8*)&Cptr[quad * 8];
    cf[1] = *(const short8*)&Cptr[32 + quad * 8];

    int trow[4];
    float cumt[4];
    #pragma unroll
    for (int r = 0; r < 4; r++) {
        trow[r] = qt * 64 + w * 16 + quad * 4 + r;
        cumt[r] = cum_arr[bh * SEQ + trow[r]];
    }
    float4v yacc[4];
    #pragma unroll
    for (int i = 0; i < 4; i++) yacc[i] = (float4v){0.f, 0.f, 0.f, 0.f};

    for (int si = 0; si < nst; si++) {
        int st = st0 + si;
        int cur = si & 1;
        __syncthreads();  // drains gld16 vmcnt -> buf[cur] published
        if (si + 1 < nst) {
            int nx = cur ^ 1;
            int stn = st + 1;
            const unsigned short* bsrc = Bh + ((size_t)bh * SEQ + stn * 64) * 64;
            gld16(&Bs[nx][tid * 8],         bsrc + srow * 64 + swz);
            gld16(&Bs[nx][(tid + 256) * 8], bsrc + (srow + 32) * 64 + swz2);
            const unsigned short* xsrc = Xt + (size_t)bh * 64 * SEQ + stn * 64;
            gld16(&Xs[nx][tid * 8],         xsrc + (size_t)srow * SEQ + swz);
            gld16(&Xs[nx][(tid + 256) * 8], xsrc + (size_t)(srow + 32) * SEQ + swz2);
        }

        // scores S[t][s] = C_t . B_s
        float4v sacc[4];
        #pragma unroll
        for (int i = 0; i < 4; i++) sacc[i] = (float4v){0.f, 0.f, 0.f, 0.f};
        #pragma unroll
        for (int kk = 0; kk < 2; kk++)
            #pragma unroll
            for (int nt = 0; nt < 4; nt++) {
                short8 bf8 = *(const short8*)&Bs[cur][(nt * 16 + l15) * 64 + (((kk << 2) + quad) ^ rx) * 8];
                sacc[nt] = __builtin_amdgcn_mfma_f32_16x16x32_bf16(cf[kk], bf8, sacc[nt], 0, 0, 0);
            }
        // weight + pack P (bf16) into per-wave swizzled LDS region
        #pragma unroll
        for (int nt = 0; nt < 4; nt++) {
            int s = st * 64 + nt * 16 + l15;
            float cums = cum_arr[bh * SEQ + s];
            float dts = dt_arr[bh * SEQ + s];
            float dts1 = (s + 1 < SEQ) ? dt_arr[bh * SEQ + s + 1] : 0.f;
            #pragma unroll
            for (int r = 0; r < 4; r++) {
                int t = trow[r];
                float wgt = (s > t) ? 0.f
                          : expf(Aneg * (cumt[r] - cums)) * 0.5f * (dts + ((s < t) ? dts1 : 0.f));
                int row = quad * 4 + r;
                int col = nt * 16 + l15;
                Ps[w * 1024 + row * 64 + (((col >> 3) ^ (row & 7)) << 3) + (col & 7)]
                    = f2bf(sacc[nt][r] * wgt);
            }
        }
        // Ps is per-wave private: same-wave lgkmcnt ordering suffices, no barrier.
        #pragma unroll
        for (int kk = 0; kk < 2; kk++) {
            short8 af = *(const short8*)&Ps[w * 1024 + l15 * 64 + (((kk << 2) + quad) ^ rx) * 8];
            #pragma unroll
            for (int pt = 0; pt < 4; pt++) {
                short8 xf = *(const short8*)&Xs[cur][(pt * 16 + l15) * 64 + (((kk << 2) + quad) ^ rx) * 8];
                yacc[pt] = __builtin_amdgcn_mfma_f32_16x16x32_bf16(af, xf, yacc[pt], 0, 0, 0);
            }
        }
    }
    float* yp = y_part + (size_t)slot * ((size_t)MROWS * D_INNER);
    #pragma unroll
    for (int pt = 0; pt < 4; pt++)
        #pragma unroll
        for (int r = 0; r < 4; r++) {
            int t = trow[r];
            int p = pt * 16 + l15;
            yp[((size_t)b * SEQ + t) * D_INNER + h * 64 + p] = yacc[pt][r];
        }
}

// ---------------------------------------------------------------------------
// y = (sum of ns(t) slot partials) * silu(z); rmsnorm; write bf16.
// ns(t) = ceil((t/64 + 1)/4). 1024 blocks x 256 thr.
// ---------------------------------------------------------------------------
__global__ __launch_bounds__(256) void gated_rmsnorm(
    const float* __restrict__ y_part, const unsigned short* __restrict__ proj,
    const float* __restrict__ nw, unsigned short* __restrict__ Y2) {
    __shared__ float red[4];
    int m = blockIdx.x, tid = threadIdx.x;
    int t = m & 511;
    int ns = ((t >> 6) + 4) >> 2;
    const unsigned short* zrow = proj + (size_t)m * PROJ_DIM;
    int j0 = tid * 8;
    float acc8[8];
    #pragma unroll
    for (int k = 0; k < 8; k++) acc8[k] = 0.f;
    for (int p = 0; p < ns; p++) {
        const float* yr = y_part + (size_t)p * ((size_t)MROWS * D_INNER) + (size_t)m * D_INNER + j0;
        float4v a = *(const float4v*)&yr[0];
        float4v c = *(const float4v*)&yr[4];
        acc8[0] += a[0]; acc8[1] += a[1]; acc8[2] += a[2]; acc8[3] += a[3];
        acc8[4] += c[0]; acc8[5] += c[1]; acc8[6] += c[2]; acc8[7] += c[3];
    }
    ushort8 zv = *(const ushort8*)&zrow[j0];
    float v[8];
    float ss = 0.f;
    #pragma unroll
    for (int k = 0; k < 8; k++) {
        float y = acc8[k];
        float z = bf2f(zv[k]);
        float g = y * (z / (1.f + expf(-z)));
        v[k] = g;
        ss += g * g;
    }
    #pragma unroll
    for (int d = 32; d > 0; d >>= 1) ss += __shfl_down(ss, d, 64);
    if ((tid & 63) == 0) red[tid >> 6] = ss;
    __syncthreads();
    float tot = red[0] + red[1] + red[2] + red[3];
    float inv = 1.0f / sqrtf(tot / (float)D_INNER + 1e-6f);
    #pragma unroll
    for (int k = 0; k < 8; k++)
        Y2[(size_t)m * D_INNER + j0 + k] = f2bf(v[k] * inv * nw[j0 + k]);
}

// ---------------------------------------------------------------------------

extern "C" void kernel_launch(void* const* d_in, const int* in_sizes, int n_in,
                              void* d_out, int out_size, void* d_ws, size_t ws_size,
                              hipStream_t stream) {
    const float* hidden   = (const float*)d_in[0];
    const float* W_in     = (const float*)d_in[1];
    const float* dt_bias  = (const float*)d_in[2];
    const float* A_log    = (const float*)d_in[3];
    const float* norm_w   = (const float*)d_in[4];
    const float* W_out    = (const float*)d_in[5];
    float* out = (float*)d_out;

    char* ws = (char*)d_ws;
    unsigned short* Wt1  = (unsigned short*)(ws);                // 8320*1024 bf16 = 17,039,360
    unsigned short* Hb   = (unsigned short*)(ws + 17039360);     // 1024*1024 bf16 = 2,097,152
    unsigned short* proj = (unsigned short*)(ws + 19136512);     // 1024*8224 bf16 = 16,842,752
    float* dt_arr        = (float*)(ws + 35979264);              // 131,072
    float* cum_arr       = (float*)(ws + 36110336);              // 131,072
    unsigned short* Bh   = (unsigned short*)(ws + 36241408);     // 4,194,304
    unsigned short* Ch   = (unsigned short*)(ws + 40435712);     // 4,194,304
    unsigned short* Xt   = (unsigned short*)(ws + 44630016);     // 4,194,304
    unsigned short* Y2   = (unsigned short*)(ws + 57212928);     // 4,194,304
    unsigned short* Wt2  = (unsigned short*)(ws + 61407232);     // 4,194,304
    float* y_part        = (float*)(ws + 65601536);              // 2 x 8,388,608 = 16,777,216
    // total 82,378,752 bytes (ws poison is 256 MiB per harness)
    float* Pk = (float*)proj;  // 16 MB split-K partials fit in 16.8 MB proj (free by then)

    // prep: hidden cast (1024) + Wt1 transpose (2080)
    prep_fat<<<3104, 256, 0, stream>>>(hidden, W_in, Hb, Wt1);
    // proj = hidden @ W_in (bf16 out, guarded at N=8224). 128x64 tiles:
    // 130x8 = 1040 blocks (~4/CU resident) for latency-hiding overlap.
    gemm_bt<true><<<dim3(130, 8, 1), 256, 0, stream>>>(
        Hb, Wt1, proj, MROWS, PROJ_DIM, D_MODEL, D_MODEL);
    // dt + cumsum (2-round parallel prefix)
    dt_scan<<<64, 256, 0, stream>>>(proj, dt_bias, dt_arr, cum_arr);
    // rope pack (1024) + x transpose (512) + Wt2 transpose (512)
    pack_fat<<<2048, 256, 0, stream>>>(proj, cum_arr, W_out, Bh, Ch, Xt, Wt2);
    // decay attention: up to 4 (qt,st) tiles per block, dbuf staging,
    // slot-partial stores
    attn_tile<<<dim3(12, 64), 256, 0, stream>>>(Bh, Ch, Xt, dt_arr, cum_arr, A_log, y_part);
    // gate + rmsnorm, inline <=2-slot reduction (last reader of proj/z)
    gated_rmsnorm<<<MROWS, 256, 0, stream>>>(y_part, proj, norm_w, Y2);
    // out = Y2 @ W_out, 128x64 tiles, split-K=4: 16x8x4 = 512 blocks
    gemm_bt<false><<<dim3(16, 8, 4), 256, 0, stream>>>(
        Y2, Wt2, Pk, MROWS, D_MODEL, D_INNER, D_INNER / 4);
    reduce4<<<MROWS * D_MODEL / 1024, 256, 0, stream>>>(Pk, out, MROWS * D_MODEL);
}

// Round 9
// 178.464 us; speedup vs baseline: 1.0453x; 1.0130x over previous
//
#include <hip/hip_runtime.h>
#include <stdint.h>

typedef __attribute__((ext_vector_type(8))) short short8;
typedef __attribute__((ext_vector_type(8))) unsigned short ushort8;
typedef __attribute__((ext_vector_type(4))) unsigned short usv4;
typedef __attribute__((ext_vector_type(4))) float float4v;

#define B_SZ 2
#define SEQ 512
#define D_MODEL 1024
#define D_INNER 2048
#define N_HEADS 32
#define HEAD_DIM 64
#define D_STATE 64
#define PROJ_DIM 8224   // 2*2048 + 2*2048 + 32
#define NPAD 8320       // 65*128
#define MROWS 1024      // B_SZ*SEQ

__device__ __forceinline__ unsigned short f2bf(float f) {
    unsigned u = __builtin_bit_cast(unsigned, f);
    u += 0x7fffu + ((u >> 16) & 1u);
    return (unsigned short)(u >> 16);
}
__device__ __forceinline__ float bf2f(unsigned short h) {
    return __builtin_bit_cast(float, (unsigned)h << 16);
}

// Async global->LDS 16B (m97 path). LDS dest must be wave-uniform base + lane*16.
__device__ __forceinline__ void gld16(unsigned short* lds, const unsigned short* g) {
#if __has_builtin(__builtin_amdgcn_global_load_lds)
    __builtin_amdgcn_global_load_lds(
        (const __attribute__((address_space(1))) void*)g,
        (__attribute__((address_space(3))) void*)lds, 16, 0, 0);
#else
    *(short8*)lds = *(const short8*)g;
#endif
}

// ---------------------------------------------------------------------------
// 64x64 f32->bf16 transpose tile body (shared by prep_fat / pack_fat).
// ---------------------------------------------------------------------------
__device__ void transpose_body(const float* __restrict__ src,
                               unsigned short* __restrict__ dst,
                               int R, int C, int bx, int by, float* T, int tid) {
    int c0 = bx * 64, r0 = by * 64;
    int row = tid >> 2, cg = (tid & 3) * 16;
    #pragma unroll
    for (int k = 0; k < 4; k++) {
        int col = cg + k * 4;
        float4v v;
        if (c0 + col + 3 < C) {
            v = *(const float4v*)&src[(size_t)(r0 + row) * C + c0 + col];
        } else {
            #pragma unroll
            for (int e = 0; e < 4; e++)
                v[e] = (c0 + col + e < C) ? src[(size_t)(r0 + row) * C + c0 + col + e] : 0.f;
        }
        *(float4v*)&T[row * 68 + col] = v;
    }
    __syncthreads();
    int drow = tid >> 2, sg = (tid & 3) * 16;
    ushort8 v[2];
    #pragma unroll
    for (int k = 0; k < 16; k++) v[k >> 3][k & 7] = f2bf(T[(sg + k) * 68 + drow]);
    unsigned short* d = &dst[(size_t)(c0 + drow) * R + r0 + sg];
    *(ushort8*)&d[0] = v[0];
    *(ushort8*)&d[8] = v[1];
}

// ---------------------------------------------------------------------------
// prep: blk<1024 -> hidden f32->bf16; else Wt1 transpose (2080 blocks).
// ---------------------------------------------------------------------------
__global__ __launch_bounds__(256) void prep_fat(
    const float* __restrict__ hidden, const float* __restrict__ W_in,
    unsigned short* __restrict__ Hb, unsigned short* __restrict__ Wt1) {
    __shared__ float T[64 * 68];
    int blk = blockIdx.x, tid = threadIdx.x;
    if (blk < 1024) {
        int i = blk * 1024 + tid * 4;
        float4v v = *(const float4v*)&hidden[i];
        usv4 o;
        #pragma unroll
        for (int k = 0; k < 4; k++) o[k] = f2bf(v[k]);
        *(usv4*)&Hb[i] = o;
    } else {
        int q = blk - 1024;  // 2080 = 130 x 16
        transpose_body(W_in, Wt1, D_MODEL, PROJ_DIM, q % 130, q / 130, T, tid);
    }
}

// ---------------------------------------------------------------------------
// GEMM: C[M][N] = A[M][K] @ Bt[N][K]^T (bf16). TMx64 tile (TM = 128 or 64),
// 4 waves, BK=64, single-buffered m97 structure (stage->barrier->compute->
// barrier). 16-24 KB LDS -> >=4 blocks/CU resident; cross-block overlap
// hides staging latency (R7/R8: blocks/CU is the lever at these shapes;
// 1/CU = 50.6us @ 12.5% MfmaUtil, 4/CU recovered the regression).
// XOR bank swizzle via pre-swizzled global source (verified): staging row rs
// writes with XOR key rs&7; read of row r uses r&7 -- rows == lanes mod 8.
// Split-K via gridDim.z; BF16OUT selects output type. Atomic-free.
// ---------------------------------------------------------------------------
template <bool BF16OUT, int TM>
__global__ __launch_bounds__(256) void gemm_bt(
    const unsigned short* __restrict__ A, const unsigned short* __restrict__ Bt,
    void* __restrict__ Cout, int M, int N, int K, int klen) {
    constexpr int MTF = TM / 64;          // 16-row m-fragments per wave
    __shared__ unsigned short As[TM * 64];
    __shared__ unsigned short Bs[4096];   // 64 x 64
    int tid = threadIdx.x;
    int lane = tid & 63, w = tid >> 6, quad = lane >> 4, l15 = lane & 15;
    int m0 = blockIdx.y * TM, n0 = blockIdx.x * 64;
    int kb = blockIdx.z * klen, ke = kb + klen;
    int wm = w * (TM / 4);
    float4v acc[MTF][4];
    #pragma unroll
    for (int i = 0; i < MTF; i++)
        #pragma unroll
        for (int j = 0; j < 4; j++) acc[i][j] = (float4v){0.f, 0.f, 0.f, 0.f};

    int rs = tid >> 3;
    int gl = ((tid & 7) ^ (rs & 7)) * 8;
    const unsigned short* ap = &A [(size_t)(m0 + rs) * K + gl];
    const unsigned short* bp = &Bt[(size_t)(n0 + rs) * K + gl];
    int rx = l15 & 7;

    for (int k0 = kb; k0 < ke; k0 += 64) {
        __syncthreads();
        #pragma unroll
        for (int p = 0; p < TM / 32; p++)
            gld16(&As[p * 2048 + tid * 8], ap + (size_t)(p * 32) * K + k0);
        #pragma unroll
        for (int p = 0; p < 2; p++)
            gld16(&Bs[p * 2048 + tid * 8], bp + (size_t)(p * 32) * K + k0);
        __syncthreads();
        #pragma unroll
        for (int kq = 0; kq < 2; kq++) {
            short8 af[MTF], bfr[4];
            #pragma unroll
            for (int mt = 0; mt < MTF; mt++)
                af[mt] = *(const short8*)&As[(wm + mt * 16 + l15) * 64 + (((kq << 2) + quad) ^ rx) * 8];
            #pragma unroll
            for (int nt = 0; nt < 4; nt++)
                bfr[nt] = *(const short8*)&Bs[(nt * 16 + l15) * 64 + (((kq << 2) + quad) ^ rx) * 8];
            #pragma unroll
            for (int mt = 0; mt < MTF; mt++)
                #pragma unroll
                for (int nt = 0; nt < 4; nt++)
                    acc[mt][nt] = __builtin_amdgcn_mfma_f32_16x16x32_bf16(
                        af[mt], bfr[nt], acc[mt][nt], 0, 0, 0);
        }
    }
    #pragma unroll
    for (int mt = 0; mt < MTF; mt++)
        #pragma unroll
        for (int nt = 0; nt < 4; nt++)
            #pragma unroll
            for (int r = 0; r < 4; r++) {
                int row = m0 + wm + mt * 16 + quad * 4 + r;
                int col = n0 + nt * 16 + l15;
                if (col < N) {
                    if (BF16OUT)
                        ((unsigned short*)Cout)[(size_t)row * N + col] = f2bf(acc[mt][nt][r]);
                    else
                        ((float*)Cout)[(size_t)blockIdx.z * M * N + (size_t)row * N + col]
                            = acc[mt][nt][r];
                }
            }
}

// ---------------------------------------------------------------------------
// reduce 4 split-K partials -> f32 out.
// ---------------------------------------------------------------------------
__global__ __launch_bounds__(256) void reduce4(
    const float* __restrict__ P, float* __restrict__ out, int n) {
    int i = (blockIdx.x * 256 + threadIdx.x) * 4;
    float4v s = *(const float4v*)&P[i];
    #pragma unroll
    for (int z = 1; z < 4; z++) {
        float4v v = *(const float4v*)&P[(size_t)z * n + i];
        #pragma unroll
        for (int k = 0; k < 4; k++) s[k] += v[k];
    }
    *(float4v*)&out[i] = s;
}

// ---------------------------------------------------------------------------
// dt softplus + cumsum per (b,h): 64 blocks x 256 threads (4 waves x 2
// chunks), 2-round parallel prefix (wave scans + 8-entry chunk-total scan).
// ---------------------------------------------------------------------------
__global__ __launch_bounds__(256) void dt_scan(
    const unsigned short* __restrict__ proj, const float* __restrict__ dt_bias,
    float* __restrict__ dt_arr, float* __restrict__ cum_arr) {
    __shared__ float chs[8];
    int bh = blockIdx.x;
    int b = bh >> 5, h = bh & 31;
    int tid = threadIdx.x, lane = tid & 63, w = tid >> 6;
    float bias = dt_bias[h];
    int t0 = w * 64 + lane, t1 = 256 + w * 64 + lane;
    float raw0 = bf2f(proj[(size_t)(b * SEQ + t0) * PROJ_DIM + 8192 + h]) + bias;
    float raw1 = bf2f(proj[(size_t)(b * SEQ + t1) * PROJ_DIM + 8192 + h]) + bias;
    float dt0 = raw0 > 20.f ? raw0 : log1pf(expf(raw0));
    float dt1 = raw1 > 20.f ? raw1 : log1pf(expf(raw1));
    float v0 = dt0, v1 = dt1;
    #pragma unroll
    for (int d = 1; d < 64; d <<= 1) {
        float n0 = __shfl_up(v0, d, 64);
        float n1 = __shfl_up(v1, d, 64);
        if (lane >= d) { v0 += n0; v1 += n1; }
    }
    if (lane == 63) { chs[w] = v0; chs[4 + w] = v1; }
    __syncthreads();
    float off0 = 0.f, off1 = 0.f;
    #pragma unroll
    for (int c = 0; c < 8; c++) {
        float s = chs[c];
        if (c < w) off0 += s;
        if (c < 4 + w) off1 += s;
    }
    dt_arr[bh * SEQ + t0] = dt0;  cum_arr[bh * SEQ + t0] = off0 + v0;
    dt_arr[bh * SEQ + t1] = dt1;  cum_arr[bh * SEQ + t1] = off1 + v1;
}

// ---------------------------------------------------------------------------
// pack_fat: blk<1024 -> RoPE pack B,C for row m=blk (b,t); blk<1536 ->
// x-transpose chunk (512 blocks) -> Xt[bh][p][s] bf16; blk<2048 -> Wt2
// transpose (512 blocks, off gemm1's critical path).
// ---------------------------------------------------------------------------
__global__ __launch_bounds__(256) void pack_fat(
    const unsigned short* __restrict__ proj, const float* __restrict__ cum_arr,
    const float* __restrict__ W_out,
    unsigned short* __restrict__ Bh, unsigned short* __restrict__ Ch,
    unsigned short* __restrict__ Xt, unsigned short* __restrict__ Wt2) {
    __shared__ float T[64 * 68];
    unsigned short* XT = (unsigned short*)T;
    int blk = blockIdx.x, tid = threadIdx.x;
    if (blk < 1024) {
        int m = blk, b = m >> 9, t = m & 511;
        const float k_l2 = 13.287712379549449f / 32.f;  // log2(10000)/half
        #pragma unroll
        for (int i = 0; i < 4; i++) {
            int q = i * 256 + tid;
            int h = q >> 5, j = q & 31;
            float cum = cum_arr[(b * 32 + h) * SEQ + t];
            float th = cum * exp2f(-(float)j * k_l2);
            float s, c;
            __sincosf(th, &s, &c);
            size_t rb = (size_t)m * PROJ_DIM;
            unsigned bu = *(const unsigned*)&proj[rb + 4096 + h * 64 + 2 * j];
            unsigned cu = *(const unsigned*)&proj[rb + 6144 + h * 64 + 2 * j];
            float b0 = bf2f((unsigned short)(bu & 0xffff)), b1 = bf2f((unsigned short)(bu >> 16));
            float c0 = bf2f((unsigned short)(cu & 0xffff)), c1 = bf2f((unsigned short)(cu >> 16));
            size_t dst = ((size_t)(b * 32 + h) * SEQ + t) * 64 + 2 * j;
            unsigned ob = (unsigned)f2bf(b0 * c - b1 * s) | ((unsigned)f2bf(b0 * s + b1 * c) << 16);
            unsigned oc = (unsigned)f2bf(c0 * c - c1 * s) | ((unsigned)f2bf(c0 * s + c1 * c) << 16);
            *(unsigned*)&Bh[dst] = ob;
            *(unsigned*)&Ch[dst] = oc;
        }
    } else if (blk < 1536) {
        int q = blk - 1024;
        int bh = q >> 3, s0 = (q & 7) * 64;
        int b = bh >> 5, h = bh & 31;
        int r = tid >> 2, cg = (tid & 3) * 16;
        const unsigned short* src = &proj[(size_t)(b * SEQ + s0 + r) * PROJ_DIM + 2048 + h * 64 + cg];
        *(ushort8*)&XT[r * 72 + cg]     = *(const ushort8*)&src[0];
        *(ushort8*)&XT[r * 72 + cg + 8] = *(const ushort8*)&src[8];
        __syncthreads();
        int p = tid >> 2, sg = (tid & 3) * 16;
        ushort8 v[2];
        #pragma unroll
        for (int k = 0; k < 16; k++) v[k >> 3][k & 7] = XT[(sg + k) * 72 + p];
        unsigned short* dst = &Xt[((size_t)bh * 64 + p) * SEQ + s0 + sg];
        *(ushort8*)&dst[0] = v[0];
        *(ushort8*)&dst[8] = v[1];
    } else {
        int q = blk - 1536;  // 512 = 16 x 32
        transpose_body(W_out, Wt2, D_INNER, D_MODEL, q % 16, q / 16, T, tid);
    }
}

// ---------------------------------------------------------------------------
// Decay-attention, up to FOUR (qt,st) tiles per block, ATOMIC-FREE, with
// double-buffered issue-early staging. slot = st-group index within qt (<=2).
// Disjoint y_part regions per (qt,slot,bh); gated_rmsnorm sums ns(t) slots.
// grid (12 slot-blocks, 64 bh), 256 threads (4 waves x 16 q-rows).
// ---------------------------------------------------------------------------
__global__ __launch_bounds__(256) void attn_tile(
    const unsigned short* __restrict__ Bh, const unsigned short* __restrict__ Ch,
    const unsigned short* __restrict__ Xt, const float* __restrict__ dt_arr,
    const float* __restrict__ cum_arr, const float* __restrict__ A_log,
    float* __restrict__ y_part) {
    __shared__ unsigned short Bs[2][4096];
    __shared__ unsigned short Xs[2][4096];
    __shared__ unsigned short Ps[4096];
    // decode slot index -> (qt, slot): qt has ceil((qt+1)/4) slot-blocks
    int pid = blockIdx.x;
    int qt = 0;
    while (pid >= ((qt + 4) >> 2)) { pid -= ((qt + 4) >> 2); qt++; }
    int slot = pid;
    int st0 = slot * 4;
    int nst = qt - st0 + 1; if (nst > 4) nst = 4;
    int bh = blockIdx.y;
    int b = bh >> 5, h = bh & 31;
    float Aneg = -expf(A_log[h]);
    int tid = threadIdx.x, lane = tid & 63, w = tid >> 6;
    int quad = lane >> 4, l15 = lane & 15;
    int rx = l15 & 7;

    int srow = tid >> 3, sg = tid & 7;
    int swz = (sg ^ (srow & 7)) * 8;
    int swz2 = (sg ^ ((srow + 32) & 7)) * 8;

    // prologue: stage first tile into buf 0
    {
        const unsigned short* bsrc = Bh + ((size_t)bh * SEQ + st0 * 64) * 64;
        gld16(&Bs[0][tid * 8],         bsrc + srow * 64 + swz);
        gld16(&Bs[0][(tid + 256) * 8], bsrc + (srow + 32) * 64 + swz2);
        const unsigned short* xsrc = Xt + (size_t)bh * 64 * SEQ + st0 * 64;
        gld16(&Xs[0][tid * 8],         xsrc + (size_t)srow * SEQ + swz);
        gld16(&Xs[0][(tid + 256) * 8], xsrc + (size_t)(srow + 32) * SEQ + swz2);
    }

    int qrow = qt * 64 + w * 16 + l15;
    const unsigned short* Cptr = Ch + ((size_t)bh * SEQ + qrow) * 64;
    short8 cf[2];
    cf[0] = *(const short8*)&Cptr[quad * 8];
    cf[1] = *(const short8*)&Cptr[32 + quad * 8];

    int trow[4];
    float cumt[4];
    #pragma unroll
    for (int r = 0; r < 4; r++) {
        trow[r] = qt * 64 + w * 16 + quad * 4 + r;
        cumt[r] = cum_arr[bh * SEQ + trow[r]];
    }
    float4v yacc[4];
    #pragma unroll
    for (int i = 0; i < 4; i++) yacc[i] = (float4v){0.f, 0.f, 0.f, 0.f};

    for (int si = 0; si < nst; si++) {
        int st = st0 + si;
        int cur = si & 1;
        __syncthreads();  // drains gld16 vmcnt -> buf[cur] published
        if (si + 1 < nst) {
            int nx = cur ^ 1;
            int stn = st + 1;
            const unsigned short* bsrc = Bh + ((size_t)bh * SEQ + stn * 64) * 64;
            gld16(&Bs[nx][tid * 8],         bsrc + srow * 64 + swz);
            gld16(&Bs[nx][(tid + 256) * 8], bsrc + (srow + 32) * 64 + swz2);
            const unsigned short* xsrc = Xt + (size_t)bh * 64 * SEQ + stn * 64;
            gld16(&Xs[nx][tid * 8],         xsrc + (size_t)srow * SEQ + swz);
            gld16(&Xs[nx][(tid + 256) * 8], xsrc + (size_t)(srow + 32) * SEQ + swz2);
        }

        // scores S[t][s] = C_t . B_s
        float4v sacc[4];
        #pragma unroll
        for (int i = 0; i < 4; i++) sacc[i] = (float4v){0.f, 0.f, 0.f, 0.f};
        #pragma unroll
        for (int kk = 0; kk < 2; kk++)
            #pragma unroll
            for (int nt = 0; nt < 4; nt++) {
                short8 bf8 = *(const short8*)&Bs[cur][(nt * 16 + l15) * 64 + (((kk << 2) + quad) ^ rx) * 8];
                sacc[nt] = __builtin_amdgcn_mfma_f32_16x16x32_bf16(cf[kk], bf8, sacc[nt], 0, 0, 0);
            }
        // weight + pack P (bf16) into per-wave swizzled LDS region
        #pragma unroll
        for (int nt = 0; nt < 4; nt++) {
            int s = st * 64 + nt * 16 + l15;
            float cums = cum_arr[bh * SEQ + s];
            float dts = dt_arr[bh * SEQ + s];
            float dts1 = (s + 1 < SEQ) ? dt_arr[bh * SEQ + s + 1] : 0.f;
            #pragma unroll
            for (int r = 0; r < 4; r++) {
                int t = trow[r];
                float wgt = (s > t) ? 0.f
                          : expf(Aneg * (cumt[r] - cums)) * 0.5f * (dts + ((s < t) ? dts1 : 0.f));
                int row = quad * 4 + r;
                int col = nt * 16 + l15;
                Ps[w * 1024 + row * 64 + (((col >> 3) ^ (row & 7)) << 3) + (col & 7)]
                    = f2bf(sacc[nt][r] * wgt);
            }
        }
        // Ps is per-wave private: same-wave lgkmcnt ordering suffices, no barrier.
        #pragma unroll
        for (int kk = 0; kk < 2; kk++) {
            short8 af = *(const short8*)&Ps[w * 1024 + l15 * 64 + (((kk << 2) + quad) ^ rx) * 8];
            #pragma unroll
            for (int pt = 0; pt < 4; pt++) {
                short8 xf = *(const short8*)&Xs[cur][(pt * 16 + l15) * 64 + (((kk << 2) + quad) ^ rx) * 8];
                yacc[pt] = __builtin_amdgcn_mfma_f32_16x16x32_bf16(af, xf, yacc[pt], 0, 0, 0);
            }
        }
    }
    float* yp = y_part + (size_t)slot * ((size_t)MROWS * D_INNER);
    #pragma unroll
    for (int pt = 0; pt < 4; pt++)
        #pragma unroll
        for (int r = 0; r < 4; r++) {
            int t = trow[r];
            int p = pt * 16 + l15;
            yp[((size_t)b * SEQ + t) * D_INNER + h * 64 + p] = yacc[pt][r];
        }
}

// ---------------------------------------------------------------------------
// y = (sum of ns(t) slot partials) * silu(z); rmsnorm; write bf16.
// ns(t) = ceil((t/64 + 1)/4). 1024 blocks x 256 thr.
// ---------------------------------------------------------------------------
__global__ __launch_bounds__(256) void gated_rmsnorm(
    const float* __restrict__ y_part, const unsigned short* __restrict__ proj,
    const float* __restrict__ nw, unsigned short* __restrict__ Y2) {
    __shared__ float red[4];
    int m = blockIdx.x, tid = threadIdx.x;
    int t = m & 511;
    int ns = ((t >> 6) + 4) >> 2;
    const unsigned short* zrow = proj + (size_t)m * PROJ_DIM;
    int j0 = tid * 8;
    float acc8[8];
    #pragma unroll
    for (int k = 0; k < 8; k++) acc8[k] = 0.f;
    for (int p = 0; p < ns; p++) {
        const float* yr = y_part + (size_t)p * ((size_t)MROWS * D_INNER) + (size_t)m * D_INNER + j0;
        float4v a = *(const float4v*)&yr[0];
        float4v c = *(const float4v*)&yr[4];
        acc8[0] += a[0]; acc8[1] += a[1]; acc8[2] += a[2]; acc8[3] += a[3];
        acc8[4] += c[0]; acc8[5] += c[1]; acc8[6] += c[2]; acc8[7] += c[3];
    }
    ushort8 zv = *(const ushort8*)&zrow[j0];
    float v[8];
    float ss = 0.f;
    #pragma unroll
    for (int k = 0; k < 8; k++) {
        float y = acc8[k];
        float z = bf2f(zv[k]);
        float g = y * (z / (1.f + expf(-z)));
        v[k] = g;
        ss += g * g;
    }
    #pragma unroll
    for (int d = 32; d > 0; d >>= 1) ss += __shfl_down(ss, d, 64);
    if ((tid & 63) == 0) red[tid >> 6] = ss;
    __syncthreads();
    float tot = red[0] + red[1] + red[2] + red[3];
    float inv = 1.0f / sqrtf(tot / (float)D_INNER + 1e-6f);
    #pragma unroll
    for (int k = 0; k < 8; k++)
        Y2[(size_t)m * D_INNER + j0 + k] = f2bf(v[k] * inv * nw[j0 + k]);
}

// ---------------------------------------------------------------------------

extern "C" void kernel_launch(void* const* d_in, const int* in_sizes, int n_in,
                              void* d_out, int out_size, void* d_ws, size_t ws_size,
                              hipStream_t stream) {
    const float* hidden   = (const float*)d_in[0];
    const float* W_in     = (const float*)d_in[1];
    const float* dt_bias  = (const float*)d_in[2];
    const float* A_log    = (const float*)d_in[3];
    const float* norm_w   = (const float*)d_in[4];
    const float* W_out    = (const float*)d_in[5];
    float* out = (float*)d_out;

    char* ws = (char*)d_ws;
    unsigned short* Wt1  = (unsigned short*)(ws);                // 8320*1024 bf16 = 17,039,360
    unsigned short* Hb   = (unsigned short*)(ws + 17039360);     // 1024*1024 bf16 = 2,097,152
    unsigned short* proj = (unsigned short*)(ws + 19136512);     // 1024*8224 bf16 = 16,842,752
    float* dt_arr        = (float*)(ws + 35979264);              // 131,072
    float* cum_arr       = (float*)(ws + 36110336);              // 131,072
    unsigned short* Bh   = (unsigned short*)(ws + 36241408);     // 4,194,304
    unsigned short* Ch   = (unsigned short*)(ws + 40435712);     // 4,194,304
    unsigned short* Xt   = (unsigned short*)(ws + 44630016);     // 4,194,304
    unsigned short* Y2   = (unsigned short*)(ws + 57212928);     // 4,194,304
    unsigned short* Wt2  = (unsigned short*)(ws + 61407232);     // 4,194,304
    float* y_part        = (float*)(ws + 65601536);              // 2 x 8,388,608 = 16,777,216
    // total 82,378,752 bytes (ws poison is 256 MiB per harness)
    float* Pk = (float*)proj;  // 16 MB split-K partials fit in 16.8 MB proj (free by then)

    // prep: hidden cast (1024) + Wt1 transpose (2080)
    prep_fat<<<3104, 256, 0, stream>>>(hidden, W_in, Hb, Wt1);
    // proj = hidden @ W_in (bf16 out, guarded at N=8224). 128x64 tiles:
    // 130x8 = 1040 blocks (~4/CU resident) for latency-hiding overlap.
    gemm_bt<true, 128><<<dim3(130, 8, 1), 256, 0, stream>>>(
        Hb, Wt1, proj, MROWS, PROJ_DIM, D_MODEL, D_MODEL);
    // dt + cumsum (2-round parallel prefix)
    dt_scan<<<64, 256, 0, stream>>>(proj, dt_bias, dt_arr, cum_arr);
    // rope pack (1024) + x transpose (512) + Wt2 transpose (512)
    pack_fat<<<2048, 256, 0, stream>>>(proj, cum_arr, W_out, Bh, Ch, Xt, Wt2);
    // decay attention: up to 4 (qt,st) tiles per block, dbuf staging,
    // slot-partial stores
    attn_tile<<<dim3(12, 64), 256, 0, stream>>>(Bh, Ch, Xt, dt_arr, cum_arr, A_log, y_part);
    // gate + rmsnorm, inline <=2-slot reduction (last reader of proj/z)
    gated_rmsnorm<<<MROWS, 256, 0, stream>>>(y_part, proj, norm_w, Y2);
    // out = Y2 @ W_out, 64x64 tiles, split-K=4: 16x16x4 = 1024 blocks (4/CU)
    gemm_bt<false, 64><<<dim3(16, 16, 4), 256, 0, stream>>>(
        Y2, Wt2, Pk, MROWS, D_MODEL, D_INNER, D_INNER / 4);
    reduce4<<<MROWS * D_MODEL / 1024, 256, 0, stream>>>(Pk, out, MROWS * D_MODEL);
}